// Round 1
// 513.594 us; speedup vs baseline: 1.0240x; 1.0240x over previous
//
#include <hip/hip_runtime.h>

typedef __attribute__((ext_vector_type(8))) short short8;
typedef __attribute__((ext_vector_type(4))) float f32x4;

constexpr int L = 1024, C = 256, F = 256;
constexpr int NIMG = 256;          // B*M
constexpr int LOUT = 1022;         // L - K + 1
constexpr long MAXROW = (long)NIMG * L - 1;

__device__ inline unsigned short f2bf(float f) {
  union { float f; unsigned u; } v; v.f = f;
  return (unsigned short)((v.u + 0x7FFFu + ((v.u >> 16) & 1u)) >> 16);  // RNE
}

__device__ inline void g2l16(const unsigned short* g, unsigned short* l) {
  __builtin_amdgcn_global_load_lds(
      (const __attribute__((address_space(1))) unsigned int*)g,
      (__attribute__((address_space(3))) unsigned int*)l, 16, 0, 0);
}

// Pre-pass: W (3,256,256) fp32 -> Wt bf16, layout [slab(8)][k(3)][fh(2)][f'(128)][kp(32)]
__global__ void wprep(const float* __restrict__ W, unsigned short* __restrict__ Wt) {
  int tid = blockIdx.x * 256 + threadIdx.x;       // exactly 768*256 threads
  int kc = tid >> 8, f = tid & 255;               // coalesced read of W[tid]
  int k = kc >> 8, c = kc & 255;
  int slab = c >> 5, kp = c & 31;
  int fh = f >> 7, fp = f & 127;
  Wt[(size_t)((((slab * 3 + k) * 2 + fh) * 128 + fp) * 32 + kp)] = f2bf(W[tid]);
}

// Pipelined schedule (T3+T4 recipe): 1 raw barrier per k-step, depth-2 B
// prefetch into triple-buffered LDS, counted vmcnt (never 0 mid-loop for
// slab<7), A reg-staged k0->k2 across the slab, dbuf As.
__global__ __launch_bounds__(256) void conv_mfma(
    const float* __restrict__ x, const unsigned short* __restrict__ Wt,
    const float* __restrict__ bias, float* __restrict__ y)
{
  __shared__ __align__(16) unsigned short As[2][130 * 32];  // 2 x 8320 B
  __shared__ __align__(16) unsigned short Bs[3][128 * 32];  // 3 x 8192 B

  const int bid = blockIdx.x;
  const int fh  = bid & 1;          // F half; paired blocks share the x tile
  const int mt  = (bid >> 1) & 7;   // 8 m-tiles of 128 rows over Lout=1022
  const int img = bid >> 4;         // 256 images
  const int l0  = mt * 128;

  const int tid  = threadIdx.x;
  const int lane = tid & 63;
  const int wv   = tid >> 6;        // 4 waves: 2x2 grid of 64x64 sub-tiles
  const int wr   = wv >> 1;
  const int wc   = wv & 1;
  const int lr   = lane & 15;
  const int quad = lane >> 4;

  f32x4 acc[4][4] = {};
  float4 av[2][2];                  // A prefetch regs (chunks tid, tid+256)
  float4 avt[2];                    // tail chunks (tid < 8)

  const long gb  = (long)img * L + l0;
  const int  qr  = tid >> 2;        // chunk row (chunk = 16 B bf16 = 8 elems)
  const int  qc8 = (tid & 3) * 8;

  auto issue_A = [&](int slab) {    // global -> regs for rows 0..129, one slab
    const int cb = slab * 32;
    long g0 = gb + qr;        if (g0 > MAXROW) g0 = MAXROW;
    long g1 = gb + qr + 64;   if (g1 > MAXROW) g1 = MAXROW;
    const float* p0 = x + g0 * C + cb + qc8;
    const float* p1 = x + g1 * C + cb + qc8;
    av[0][0] = *(const float4*)p0; av[0][1] = *(const float4*)(p0 + 4);
    av[1][0] = *(const float4*)p1; av[1][1] = *(const float4*)(p1 + 4);
    if (tid < 8) {
      long g2 = gb + 128 + (tid >> 2); if (g2 > MAXROW) g2 = MAXROW;
      const float* p2 = x + g2 * C + cb + (tid & 3) * 8;
      avt[0] = *(const float4*)p2; avt[1] = *(const float4*)(p2 + 4);
    }
  };

  auto pack8 = [&](float4 a, float4 b) {
    short8 r;
    r[0] = (short)f2bf(a.x); r[1] = (short)f2bf(a.y);
    r[2] = (short)f2bf(a.z); r[3] = (short)f2bf(a.w);
    r[4] = (short)f2bf(b.x); r[5] = (short)f2bf(b.y);
    r[6] = (short)f2bf(b.z); r[7] = (short)f2bf(b.w);
    return r;
  };

  auto write_A = [&](int ab) {      // 520 chunks of 16 B, contiguous per wave
    *(short8*)(As[ab] + (size_t)tid * 8)         = pack8(av[0][0], av[0][1]);
    *(short8*)(As[ab] + (size_t)(tid + 256) * 8) = pack8(av[1][0], av[1][1]);
    if (tid < 8)
      *(short8*)(As[ab] + (size_t)(512 + tid) * 8) = pack8(avt[0], avt[1]);
  };

  auto stage_B = [&](int tile, int bb) {  // 8 KB contiguous, global->LDS, 2 loads/thread
    const unsigned short* bsrc = Wt + (size_t)(tile * 2 + fh) * 4096;
    g2l16(bsrc + (size_t)tid * 8,         Bs[bb] + (size_t)tid * 8);
    g2l16(bsrc + (size_t)(tid + 256) * 8, Bs[bb] + (size_t)(tid + 256) * 8);
  };

  // ---- prologue: issue order = A(0) loads, B tile0, B tile1 ----
  issue_A(0);
  stage_B(0, 0);
  stage_B(1, 1);
  write_A(0);                                   // compiler-inserted wait covers av
  // need: tile0 landed (leave tile1's 2 loads in flight), As[0] writes visible
  asm volatile("s_waitcnt vmcnt(2) lgkmcnt(0)" ::: "memory");
  __builtin_amdgcn_s_barrier();
  __builtin_amdgcn_sched_barrier(0);

  for (int slab = 0; slab < 8; ++slab) {
    const int ab = slab & 1;
#pragma unroll
    for (int k = 0; k < 3; ++k) {
      // VMEM issue order per step (matters for vmcnt counts):
      // 1) B stage for tile t+2 (2 loads), 2) A issue at k==0 (4 loads; wave0 +2)
      if (slab < 7 || k == 0)                       // tiles 2..23, each once
        stage_B(slab * 3 + k + 2, (k + 2) % 3);     // buffer idx compile-time per k
      if (k == 0 && slab < 7) issue_A(slab + 1);

      short8 af[4], bf[4];
#pragma unroll
      for (int mi = 0; mi < 4; ++mi)                // A[m=lr][kk], +k row shift
        af[mi] = *(const short8*)(As[ab] + (wr * 64 + mi * 16 + lr + k) * 32 + quad * 8);
#pragma unroll
      for (int ni = 0; ni < 4; ++ni)                // B stored [n][kk]; tile t -> Bs[k]
        bf[ni] = *(const short8*)(Bs[k] + (wc * 64 + ni * 16 + lr) * 32 + quad * 8);

      if (k == 2 && slab < 7) write_A(ab ^ 1);      // pack+write next slab's A (other buf)

      __builtin_amdgcn_s_setprio(1);
#pragma unroll
      for (int mi = 0; mi < 4; ++mi)
#pragma unroll
        for (int ni = 0; ni < 4; ++ni)
          acc[mi][ni] = __builtin_amdgcn_mfma_f32_16x16x32_bf16(af[mi], bf[ni], acc[mi][ni], 0, 0, 0);
      __builtin_amdgcn_s_setprio(0);

      // End of step t: tile t+1's B (issued at t-1) must be complete.
      // In-order vmcnt: count VMEM issued after it.
      //  slab<7:  k0: B(t+2)=2 + A=4 -> 6 | k1: A@k0=4 + B(t+2)=2 -> 6 | k2: B(t+2)=2 -> 2
      //  slab==7: k0: B(23)=2 -> 2      | k1: nothing -> 0            | k2: last step
      if (slab * 3 + k < 23) {
        if (slab < 7) {
          if (k < 2) asm volatile("s_waitcnt vmcnt(6)" ::: "memory");
          else       asm volatile("s_waitcnt vmcnt(2) lgkmcnt(0)" ::: "memory"); // + ds_writes visible
        } else {
          if (k == 0) asm volatile("s_waitcnt vmcnt(2)" ::: "memory");
          else        asm volatile("s_waitcnt vmcnt(0)" ::: "memory");
        }
        __builtin_amdgcn_s_barrier();
        __builtin_amdgcn_sched_barrier(0);
      }
    }
  }

  // Epilogue: C/D layout col=lane&15, row=quad*4+reg (m89/m91-verified)
  float bv[4];
#pragma unroll
  for (int ni = 0; ni < 4; ++ni)
    bv[ni] = bias[fh * 128 + wc * 64 + ni * 16 + lr];

#pragma unroll
  for (int mi = 0; mi < 4; ++mi) {
#pragma unroll
    for (int r = 0; r < 4; ++r) {
      const int lrow = l0 + wr * 64 + mi * 16 + quad * 4 + r;
      if (lrow < LOUT) {
        float* yp = y + ((size_t)img * LOUT + lrow) * F + fh * 128 + wc * 64 + lr;
#pragma unroll
        for (int ni = 0; ni < 4; ++ni)
          yp[ni * 16] = acc[mi][ni][r] + bv[ni];
      }
    }
  }
}

extern "C" void kernel_launch(void* const* d_in, const int* in_sizes, int n_in,
                              void* d_out, int out_size, void* d_ws, size_t ws_size,
                              hipStream_t stream) {
  const float* x = (const float*)d_in[0];   // (8,32,1024,256) fp32
  const float* W = (const float*)d_in[1];   // (3,256,256) fp32
  const float* b = (const float*)d_in[2];   // (256,) fp32
  float* y = (float*)d_out;                 // (8,32,1022,256) fp32
  unsigned short* Wt = (unsigned short*)d_ws;  // 393,216 B

  wprep<<<768, 256, 0, stream>>>(W, Wt);
  conv_mfma<<<NIMG * 8 * 2, 256, 0, stream>>>(x, Wt, b, y);
}

// Round 2
// 469.206 us; speedup vs baseline: 1.1208x; 1.0946x over previous
//
#include <hip/hip_runtime.h>

typedef __attribute__((ext_vector_type(8))) short short8;
typedef __attribute__((ext_vector_type(4))) float f32x4;

constexpr int L = 1024, C = 256, F = 256;
constexpr int NIMG = 256;          // B*M
constexpr int LOUT = 1022;         // L - K + 1
constexpr long MAXROW = (long)NIMG * L - 1;

__device__ inline unsigned short f2bf(float f) {
  union { float f; unsigned u; } v; v.f = f;
  return (unsigned short)((v.u + 0x7FFFu + ((v.u >> 16) & 1u)) >> 16);  // RNE
}

__device__ inline void g2l16(const unsigned short* g, unsigned short* l) {
  __builtin_amdgcn_global_load_lds(
      (const __attribute__((address_space(1))) unsigned int*)g,
      (__attribute__((address_space(3))) unsigned int*)l, 16, 0, 0);
}

// Pre-pass: W (3,256,256) fp32 -> Wt bf16, layout [tile(slab*3+k)][f(256)][kp(32)]
// so each main-kernel B tile (256x32 bf16 = 16 KB) is one contiguous chunk.
__global__ void wprep(const float* __restrict__ W, unsigned short* __restrict__ Wt) {
  int tid = blockIdx.x * 256 + threadIdx.x;       // exactly 768*256 threads
  int kc = tid >> 8, f = tid & 255;               // coalesced read of W[tid]
  int k = kc >> 8, c = kc & 255;
  int slab = c >> 5, kp = c & 31;
  Wt[(size_t)(((slab * 3 + k) * 256 + f) * 32 + kp)] = f2bf(W[tid]);
}

// 512-thread block computes a 128(L)x256(F) output tile (fh folded: A staged once).
// Schedule: 1 raw barrier/step, counted vmcnt (never full drain mid-loop),
// Bs tri-buffered dist-2 (t mod 3 == k so Bs[k] is the read buffer),
// A reg-issued at k0, packed+written at k2 (FIFO-max 2-step cover).
__global__ __launch_bounds__(512, 4) void conv_mfma(
    const float* __restrict__ x, const unsigned short* __restrict__ Wt,
    const float* __restrict__ bias, float* __restrict__ y)
{
  __shared__ __align__(16) unsigned short As[2][520 * 8];   // 2 x 8320 B (130 rows x 32 bf16)
  __shared__ __align__(16) unsigned short Bs[3][512 * 16];  // 3 x 16384 B (256 f x 32 bf16)

  const int bid = blockIdx.x;       // 2048 blocks
  const int mt  = bid & 7;          // 8 m-tiles of 128 rows over Lout=1022
  const int img = bid >> 3;         // 256 images
  const int l0  = mt * 128;

  const int tid  = threadIdx.x;
  const int lane = tid & 63;
  const int wv   = tid >> 6;        // 8 waves: 2(M) x 4(F) grid of 64x64 sub-tiles
  const int wr   = wv >> 2;
  const int wc   = wv & 3;
  const int lr   = lane & 15;
  const int quad = lane >> 4;

  f32x4 acc[4][4] = {};
  float4 av[2];                     // A chunk tid (8 fp32 = 32 B source)
  float4 avt[2];                    // tail chunks 512..519 (tid < 8)

  const long gb = (long)img * L + l0;

  auto issue_A = [&](int slab) {    // global -> regs, rows 0..129 of slab (fp32)
    const int cb = slab * 32;
    long g0 = gb + (tid >> 2); if (g0 > MAXROW) g0 = MAXROW;   // clamped rows feed
    const float* p0 = x + g0 * C + cb + (tid & 3) * 8;         // only masked outputs
    av[0] = *(const float4*)p0; av[1] = *(const float4*)(p0 + 4);
    if (tid < 8) {
      long g2 = gb + 128 + (tid >> 2); if (g2 > MAXROW) g2 = MAXROW;
      const float* p2 = x + g2 * C + cb + (tid & 3) * 8;
      avt[0] = *(const float4*)p2; avt[1] = *(const float4*)(p2 + 4);
    }
  };

  auto pack8 = [&](float4 a, float4 b) {
    short8 r;
    r[0] = (short)f2bf(a.x); r[1] = (short)f2bf(a.y);
    r[2] = (short)f2bf(a.z); r[3] = (short)f2bf(a.w);
    r[4] = (short)f2bf(b.x); r[5] = (short)f2bf(b.y);
    r[6] = (short)f2bf(b.z); r[7] = (short)f2bf(b.w);
    return r;
  };

  auto write_A = [&](int ab2) {     // 520 chunks of 16 B, contiguous -> balanced banks
    *(short8*)(As[ab2] + (size_t)tid * 8) = pack8(av[0], av[1]);
    if (tid < 8)
      *(short8*)(As[ab2] + (size_t)(512 + tid) * 8) = pack8(avt[0], avt[1]);
  };

  auto stage_B = [&](int tile, int bb) {  // 16 KB contiguous, 2 g2l16/thread (exact)
    const unsigned short* bsrc = Wt + (size_t)tile * 8192;
    g2l16(bsrc + (size_t)tid * 8,         Bs[bb] + (size_t)tid * 8);
    g2l16(bsrc + (size_t)(tid + 512) * 8, Bs[bb] + (size_t)(tid + 512) * 8);
  };

  // ---- prologue: av(slab0), B0, B1 in flight; As[0] written (waits av internally)
  issue_A(0);
  stage_B(0, 0);
  stage_B(1, 1);
  write_A(0);

  for (int slab = 0; slab < 8; ++slab) {
    const int ab = slab & 1;
#pragma unroll
    for (int k = 0; k < 3; ++k) {
      // Top-of-step wait: force B(t) (staged at t-2) + (k0) As writes visible.
      // FIFO accounting per wave (stage_B first, then av in each k0 step):
      //  slab<7:  k0: leave B(t+1)=2            -> vmcnt(2) lgkm(0)
      //           k1: leave B(t+1)+av=4 (w0 +avt, drained harmlessly) -> vmcnt(4)
      //           k2: leave av+B(t+1)=4         -> vmcnt(4)
      //  slab==7: no av in flight -> 2 / 2 / 0
      if (slab < 7) {
        if (k == 0)      asm volatile("s_waitcnt vmcnt(2) lgkmcnt(0)" ::: "memory");
        else             asm volatile("s_waitcnt vmcnt(4)" ::: "memory");
      } else {
        if (k == 0)      asm volatile("s_waitcnt vmcnt(2) lgkmcnt(0)" ::: "memory");
        else if (k == 1) asm volatile("s_waitcnt vmcnt(2)" ::: "memory");
        else             asm volatile("s_waitcnt vmcnt(0)" ::: "memory");
      }
      __builtin_amdgcn_s_barrier();
      __builtin_amdgcn_sched_barrier(0);

      const int t = slab * 3 + k;
      if (t < 22) stage_B(t + 2, (k + 2) % 3);      // dist-2; buf idx compile-time
      if (k == 0 && slab < 7) issue_A(slab + 1);    // 2-step reg cover (FIFO max)

      short8 af[4], bf[4];
#pragma unroll
      for (int mi = 0; mi < 4; ++mi)                // A[m=lr][kk=quad*8+j], +k row shift
        af[mi] = *(const short8*)(As[ab] + (wr * 64 + mi * 16 + lr + k) * 32 + quad * 8);
#pragma unroll
      for (int ni = 0; ni < 4; ++ni)                // B stored [f][kk]
        bf[ni] = *(const short8*)(Bs[k] + (wc * 64 + ni * 16 + lr) * 32 + quad * 8);

      __builtin_amdgcn_s_setprio(1);
#pragma unroll
      for (int mi = 0; mi < 4; ++mi)
#pragma unroll
        for (int ni = 0; ni < 4; ++ni)
          acc[mi][ni] = __builtin_amdgcn_mfma_f32_16x16x32_bf16(af[mi], bf[ni], acc[mi][ni], 0, 0, 0);
      __builtin_amdgcn_s_setprio(0);

      if (k == 2 && slab < 7) write_A(ab ^ 1);      // pack next slab's A (other buffer)
    }
  }

  // Epilogue: C/D layout col=lane&15, row=quad*4+reg (m89/m91-verified)
  float bv[4];
#pragma unroll
  for (int ni = 0; ni < 4; ++ni)
    bv[ni] = bias[wc * 64 + ni * 16 + lr];

#pragma unroll
  for (int mi = 0; mi < 4; ++mi) {
#pragma unroll
    for (int r = 0; r < 4; ++r) {
      const int lrow = l0 + wr * 64 + mi * 16 + quad * 4 + r;
      if (lrow < LOUT) {
        float* yp = y + ((size_t)img * LOUT + lrow) * F + wc * 64 + lr;
#pragma unroll
        for (int ni = 0; ni < 4; ++ni)
          yp[ni * 16] = acc[mi][ni][r] + bv[ni];
      }
    }
  }
}

extern "C" void kernel_launch(void* const* d_in, const int* in_sizes, int n_in,
                              void* d_out, int out_size, void* d_ws, size_t ws_size,
                              hipStream_t stream) {
  const float* x = (const float*)d_in[0];   // (8,32,1024,256) fp32
  const float* W = (const float*)d_in[1];   // (3,256,256) fp32
  const float* b = (const float*)d_in[2];   // (256,) fp32
  float* y = (float*)d_out;                 // (8,32,1022,256) fp32
  unsigned short* Wt = (unsigned short*)d_ws;  // 3*256*256*2 = 393,216 B

  wprep<<<768, 256, 0, stream>>>(W, Wt);
  conv_mfma<<<NIMG * 8, 512, 0, stream>>>(x, Wt, b, y);
}